// Round 1
// baseline (867.963 us; speedup 1.0000x reference)
//
#include <hip/hip_runtime.h>

#define BB   8
#define MM   2048
#define DD   1024
#define FF   2048
#define NE   32
#define PP   4
#define NPS  128     // NE*PP
#define BMR  16384   // BB*MM

// ---------------------------------------------------------------------------
// K1: logits = x @ phi ; E = exp(logits); combine = E/rowsum(E) (softmax over
// the 128 slots); atomicAdd partial column sums (for dispatch softmax over m).
// Tile: 32 rows x 128 cols, K=1024. grid=512, block=256, 16 acc/thread.
// ---------------------------------------------------------------------------
__global__ __launch_bounds__(256) void k1_logits_kernel(
    const float* __restrict__ x, const float* __restrict__ phi,
    float* __restrict__ Ebuf, float* __restrict__ Cbuf, float* __restrict__ colsum)
{
    __shared__ __align__(16) float a_lds[32][36];   // [k][row], pad 36 keeps float4 16B-aligned
    __shared__ __align__(16) float b_lds[32][128];  // [k][col]
    const int tid  = threadIdx.x;
    const int row0 = blockIdx.x * 32;
    const int bidx = row0 >> 11;            // batch (M=2048 divisible by 32)
    const int c4 = tid & 31, r4 = tid >> 5;
    const int c0 = c4 * 4,   r0 = r4 * 4;
    const int kk = tid & 31, rr0 = tid >> 5;

    float acc[4][4] = {};
    for (int kt = 0; kt < 32; ++kt) {
        const int k0 = kt * 32;
        #pragma unroll
        for (int i = 0; i < 4; ++i) {
            const int rr = rr0 + 8 * i;
            a_lds[kk][rr] = x[(size_t)(row0 + rr) * DD + k0 + kk];
        }
        #pragma unroll
        for (int i = 0; i < 4; ++i) {
            const int idx = tid + 256 * i;
            const int bkk = idx >> 5, bc = (idx & 31) * 4;
            *(float4*)&b_lds[bkk][bc] = *(const float4*)&phi[(size_t)(k0 + bkk) * NPS + bc];
        }
        __syncthreads();
        #pragma unroll
        for (int k = 0; k < 32; ++k) {
            const float4 av4 = *(const float4*)&a_lds[k][r0];
            const float4 bv4 = *(const float4*)&b_lds[k][c0];
            const float ar[4] = {av4.x, av4.y, av4.z, av4.w};
            const float br[4] = {bv4.x, bv4.y, bv4.z, bv4.w};
            #pragma unroll
            for (int i = 0; i < 4; ++i)
                #pragma unroll
                for (int j = 0; j < 4; ++j)
                    acc[i][j] = fmaf(ar[i], br[j], acc[i][j]);
        }
        __syncthreads();
    }

    // E = exp(logits). |logits| <~ 5 so exp without max-subtraction is safe.
    float e[4][4];
    #pragma unroll
    for (int i = 0; i < 4; ++i)
        #pragma unroll
        for (int j = 0; j < 4; ++j)
            e[i][j] = __expf(acc[i][j]);

    #pragma unroll
    for (int i = 0; i < 4; ++i) {
        float4 v = make_float4(e[i][0], e[i][1], e[i][2], e[i][3]);
        *(float4*)&Ebuf[(size_t)(row0 + r0 + i) * NPS + c0] = v;
    }

    // row sums over all 128 cols (this block owns the full row) -> combine
    #pragma unroll
    for (int i = 0; i < 4; ++i)
        a_lds[r0 + i][c4] = e[i][0] + e[i][1] + e[i][2] + e[i][3];
    __syncthreads();
    float inv[4];
    #pragma unroll
    for (int i = 0; i < 4; ++i) {
        float s = 0.f;
        for (int c = 0; c < 32; ++c) s += a_lds[r0 + i][c];
        inv[i] = 1.0f / s;
    }
    #pragma unroll
    for (int i = 0; i < 4; ++i) {
        float4 v = make_float4(e[i][0] * inv[i], e[i][1] * inv[i],
                               e[i][2] * inv[i], e[i][3] * inv[i]);
        *(float4*)&Cbuf[(size_t)(row0 + r0 + i) * NPS + c0] = v;
    }

    // partial column sums over this block's 32 rows -> one atomic per col
    float* bred = &b_lds[0][0];
    #pragma unroll
    for (int j = 0; j < 4; ++j)
        bred[(c0 + j) * 8 + r4] = e[0][j] + e[1][j] + e[2][j] + e[3][j];
    __syncthreads();
    if (tid < NPS) {
        float s = 0.f;
        #pragma unroll
        for (int g = 0; g < 8; ++g) s += bred[tid * 8 + g];
        atomicAdd(&colsum[bidx * NPS + tid], s);
    }
}

// ---------------------------------------------------------------------------
// K2: xs[b,np,d] = (1/colsum[b,np]) * sum_m E[b,m,np] * x[b,m,d]
// Tile: 32 np x 64 d, K=2048. grid = 8*4*16 = 512, block=256, 8 acc/thread.
// ---------------------------------------------------------------------------
__global__ __launch_bounds__(256) void k2_xs_kernel(
    const float* __restrict__ Ebuf, const float* __restrict__ x,
    const float* __restrict__ colsum, float* __restrict__ xs)
{
    __shared__ __align__(16) float a_lds[32][34];  // [k=m][row=np], pad 34 -> 8B-aligned float2
    __shared__ __align__(16) float b_lds[32][64];  // [k=m][col=d]
    const int tid = threadIdx.x;
    const int bx  = blockIdx.x;
    const int bidx = bx >> 6;
    const int rem  = bx & 63;
    const int np0  = (rem >> 4) * 32;
    const int d0   = (rem & 15) * 64;
    const int cg = tid & 15, rg = tid >> 4;
    const int kk = tid & 31, rr0 = tid >> 5;

    float acc[2][4] = {};
    for (int kt = 0; kt < 64; ++kt) {
        const int m0 = kt * 32;
        #pragma unroll
        for (int i = 0; i < 4; ++i) {
            const int mm = rr0 + 8 * i;
            a_lds[mm][kk] = Ebuf[((size_t)bidx * MM + m0 + mm) * NPS + np0 + kk];
        }
        #pragma unroll
        for (int i = 0; i < 2; ++i) {
            const int idx = tid + 256 * i;
            const int mm = idx >> 4, cc = (idx & 15) * 4;
            *(float4*)&b_lds[mm][cc] =
                *(const float4*)&x[((size_t)bidx * MM + m0 + mm) * DD + d0 + cc];
        }
        __syncthreads();
        #pragma unroll
        for (int k = 0; k < 32; ++k) {
            const float2 av2 = *(const float2*)&a_lds[k][rg * 2];
            const float4 bv4 = *(const float4*)&b_lds[k][cg * 4];
            const float ar[2] = {av2.x, av2.y};
            const float br[4] = {bv4.x, bv4.y, bv4.z, bv4.w};
            #pragma unroll
            for (int i = 0; i < 2; ++i)
                #pragma unroll
                for (int j = 0; j < 4; ++j)
                    acc[i][j] = fmaf(ar[i], br[j], acc[i][j]);
        }
        __syncthreads();
    }
    #pragma unroll
    for (int i = 0; i < 2; ++i) {
        const int np = np0 + rg * 2 + i;
        const float inv = 1.0f / colsum[bidx * NPS + np];
        float4 v = make_float4(acc[i][0] * inv, acc[i][1] * inv,
                               acc[i][2] * inv, acc[i][3] * inv);
        *(float4*)&xs[((size_t)bidx * NPS + np) * DD + d0 + cg * 4] = v;
    }
}

// ---------------------------------------------------------------------------
// K3: h = relu(xs @ w1 + b1)^2 per expert. Rows = 32 (b,p) pairs, K=1024.
// Tile 32x128, grid = 32*16 = 512, block=256, 16 acc/thread.
// Streams w1 (268 MB) -> register-prefetch double buffering.
// ---------------------------------------------------------------------------
__global__ __launch_bounds__(256) void k3_ffn1_kernel(
    const float* __restrict__ xs, const float* __restrict__ w1,
    const float* __restrict__ b1, float* __restrict__ h)
{
    __shared__ __align__(16) float a_lds[32][36];
    __shared__ __align__(16) float b_lds[32][128];
    const int tid = threadIdx.x;
    const int n  = blockIdx.x >> 4;
    const int f0 = (blockIdx.x & 15) * 128;
    const int c4 = tid & 31, r4 = tid >> 5;
    const int c0 = c4 * 4,   r0 = r4 * 4;
    const int kk = tid & 31, rr0 = tid >> 5;

    size_t a_base[4];
    #pragma unroll
    for (int i = 0; i < 4; ++i) {
        const int rr = rr0 + 8 * i;
        const int bi = rr >> 2, p = rr & 3;
        a_base[i] = ((size_t)bi * NPS + n * PP + p) * DD + kk;
    }
    const size_t w_row = (size_t)n * DD;

    float  a_reg[4];
    float4 b_reg[4];
    #pragma unroll
    for (int i = 0; i < 4; ++i) a_reg[i] = xs[a_base[i]];
    #pragma unroll
    for (int i = 0; i < 4; ++i) {
        const int idx = tid + 256 * i;
        const int bkk = idx >> 5, bc = (idx & 31) * 4;
        b_reg[i] = *(const float4*)&w1[(w_row + bkk) * FF + f0 + bc];
    }

    float acc[4][4] = {};
    for (int kt = 0; kt < 32; ++kt) {
        #pragma unroll
        for (int i = 0; i < 4; ++i) a_lds[kk][rr0 + 8 * i] = a_reg[i];
        #pragma unroll
        for (int i = 0; i < 4; ++i) {
            const int idx = tid + 256 * i;
            *(float4*)&b_lds[idx >> 5][(idx & 31) * 4] = b_reg[i];
        }
        __syncthreads();
        if (kt < 31) {
            const int k0 = (kt + 1) * 32;
            #pragma unroll
            for (int i = 0; i < 4; ++i) a_reg[i] = xs[a_base[i] + k0];
            #pragma unroll
            for (int i = 0; i < 4; ++i) {
                const int idx = tid + 256 * i;
                const int bkk = idx >> 5, bc = (idx & 31) * 4;
                b_reg[i] = *(const float4*)&w1[(w_row + k0 + bkk) * FF + f0 + bc];
            }
        }
        #pragma unroll
        for (int k = 0; k < 32; ++k) {
            const float4 av4 = *(const float4*)&a_lds[k][r0];
            const float4 bv4 = *(const float4*)&b_lds[k][c0];
            const float ar[4] = {av4.x, av4.y, av4.z, av4.w};
            const float br[4] = {bv4.x, bv4.y, bv4.z, bv4.w};
            #pragma unroll
            for (int i = 0; i < 4; ++i)
                #pragma unroll
                for (int j = 0; j < 4; ++j)
                    acc[i][j] = fmaf(ar[i], br[j], acc[i][j]);
        }
        __syncthreads();
    }

    const float4 b1v = *(const float4*)&b1[n * FF + f0 + c0];
    const float bb1[4] = {b1v.x, b1v.y, b1v.z, b1v.w};
    #pragma unroll
    for (int i = 0; i < 4; ++i) {
        const int rr = r0 + i;
        const int bi = rr >> 2, p = rr & 3;
        float v[4];
        #pragma unroll
        for (int j = 0; j < 4; ++j) {
            float t = fmaxf(acc[i][j] + bb1[j], 0.0f);
            v[j] = t * t;
        }
        *(float4*)&h[((size_t)bi * NPS + n * PP + p) * FF + f0 + c0] =
            make_float4(v[0], v[1], v[2], v[3]);
    }
}

// ---------------------------------------------------------------------------
// K4: y = h @ w2 + b2 per expert. Rows = 32, K=2048, cols tile 64.
// grid = 32*16 = 512, block=256, 8 acc/thread. Streams w2 (268 MB).
// ---------------------------------------------------------------------------
__global__ __launch_bounds__(256) void k4_ffn2_kernel(
    const float* __restrict__ h, const float* __restrict__ w2,
    const float* __restrict__ b2, float* __restrict__ y)
{
    __shared__ __align__(16) float a_lds[32][34];
    __shared__ __align__(16) float b_lds[32][64];
    const int tid = threadIdx.x;
    const int n  = blockIdx.x >> 4;
    const int d0 = (blockIdx.x & 15) * 64;
    const int cg = tid & 15, rg = tid >> 4;
    const int kk = tid & 31, rr0 = tid >> 5;

    size_t a_base[4];
    #pragma unroll
    for (int i = 0; i < 4; ++i) {
        const int rr = rr0 + 8 * i;
        const int bi = rr >> 2, p = rr & 3;
        a_base[i] = ((size_t)bi * NPS + n * PP + p) * FF + kk;
    }
    const size_t w_base = (size_t)n * FF;

    float  a_reg[4];
    float4 b_reg[2];
    #pragma unroll
    for (int i = 0; i < 4; ++i) a_reg[i] = h[a_base[i]];
    #pragma unroll
    for (int i = 0; i < 2; ++i) {
        const int idx = tid + 256 * i;
        const int bkk = idx >> 4, cc = (idx & 15) * 4;
        b_reg[i] = *(const float4*)&w2[(w_base + bkk) * DD + d0 + cc];
    }

    float acc[2][4] = {};
    for (int kt = 0; kt < 64; ++kt) {
        #pragma unroll
        for (int i = 0; i < 4; ++i) a_lds[kk][rr0 + 8 * i] = a_reg[i];
        #pragma unroll
        for (int i = 0; i < 2; ++i) {
            const int idx = tid + 256 * i;
            *(float4*)&b_lds[idx >> 4][(idx & 15) * 4] = b_reg[i];
        }
        __syncthreads();
        if (kt < 63) {
            const int k0 = (kt + 1) * 32;
            #pragma unroll
            for (int i = 0; i < 4; ++i) a_reg[i] = h[a_base[i] + k0];
            #pragma unroll
            for (int i = 0; i < 2; ++i) {
                const int idx = tid + 256 * i;
                const int bkk = idx >> 4, cc = (idx & 15) * 4;
                b_reg[i] = *(const float4*)&w2[(w_base + k0 + bkk) * DD + d0 + cc];
            }
        }
        #pragma unroll
        for (int k = 0; k < 32; ++k) {
            const float2 av2 = *(const float2*)&a_lds[k][rg * 2];
            const float4 bv4 = *(const float4*)&b_lds[k][cg * 4];
            const float ar[2] = {av2.x, av2.y};
            const float br[4] = {bv4.x, bv4.y, bv4.z, bv4.w};
            #pragma unroll
            for (int i = 0; i < 2; ++i)
                #pragma unroll
                for (int j = 0; j < 4; ++j)
                    acc[i][j] = fmaf(ar[i], br[j], acc[i][j]);
        }
        __syncthreads();
    }

    const float4 b2v = *(const float4*)&b2[n * DD + d0 + cg * 4];
    #pragma unroll
    for (int i = 0; i < 2; ++i) {
        const int rr = rg * 2 + i;
        const int bi = rr >> 2, p = rr & 3;
        float4 v = make_float4(acc[i][0] + b2v.x, acc[i][1] + b2v.y,
                               acc[i][2] + b2v.z, acc[i][3] + b2v.w);
        *(float4*)&y[((size_t)bi * NPS + n * PP + p) * DD + d0 + cg * 4] = v;
    }
}

// ---------------------------------------------------------------------------
// K5: out[b,m,d] = sum_np combine[b,m,np] * y[b,np,d].  K=128.
// Tile 32 m x 128 d. grid = 8*64*8 = 4096, block=256, 16 acc/thread.
// ---------------------------------------------------------------------------
__global__ __launch_bounds__(256) void k5_out_kernel(
    const float* __restrict__ Cbuf, const float* __restrict__ y,
    float* __restrict__ out)
{
    __shared__ __align__(16) float a_lds[32][36];
    __shared__ __align__(16) float b_lds[32][128];
    const int tid = threadIdx.x;
    const int bx  = blockIdx.x;
    const int bidx = bx >> 9;
    const int rem  = bx & 511;
    const int m0 = (rem >> 3) * 32;
    const int d0 = (rem & 7) * 128;
    const int c4 = tid & 31, r4 = tid >> 5;
    const int c0 = c4 * 4,   r0 = r4 * 4;
    const int kk = tid & 31, rr0 = tid >> 5;

    float acc[4][4] = {};
    for (int kt = 0; kt < 4; ++kt) {
        const int k0 = kt * 32;
        #pragma unroll
        for (int i = 0; i < 4; ++i) {
            const int rr = rr0 + 8 * i;
            a_lds[kk][rr] = Cbuf[((size_t)bidx * MM + m0 + rr) * NPS + k0 + kk];
        }
        #pragma unroll
        for (int i = 0; i < 4; ++i) {
            const int idx = tid + 256 * i;
            const int bkk = idx >> 5, bc = (idx & 31) * 4;
            *(float4*)&b_lds[bkk][bc] =
                *(const float4*)&y[((size_t)bidx * NPS + k0 + bkk) * DD + d0 + bc];
        }
        __syncthreads();
        #pragma unroll
        for (int k = 0; k < 32; ++k) {
            const float4 av4 = *(const float4*)&a_lds[k][r0];
            const float4 bv4 = *(const float4*)&b_lds[k][c0];
            const float ar[4] = {av4.x, av4.y, av4.z, av4.w};
            const float br[4] = {bv4.x, bv4.y, bv4.z, bv4.w};
            #pragma unroll
            for (int i = 0; i < 4; ++i)
                #pragma unroll
                for (int j = 0; j < 4; ++j)
                    acc[i][j] = fmaf(ar[i], br[j], acc[i][j]);
        }
        __syncthreads();
    }
    #pragma unroll
    for (int i = 0; i < 4; ++i) {
        float4 v = make_float4(acc[i][0], acc[i][1], acc[i][2], acc[i][3]);
        *(float4*)&out[((size_t)bidx * MM + m0 + r0 + i) * DD + d0 + c0] = v;
    }
}

// ---------------------------------------------------------------------------
extern "C" void kernel_launch(void* const* d_in, const int* in_sizes, int n_in,
                              void* d_out, int out_size, void* d_ws, size_t ws_size,
                              hipStream_t stream)
{
    const float* x   = (const float*)d_in[0];
    const float* phi = (const float*)d_in[1];
    const float* w1  = (const float*)d_in[2];
    const float* b1  = (const float*)d_in[3];
    const float* w2  = (const float*)d_in[4];
    const float* b2  = (const float*)d_in[5];
    float* out = (float*)d_out;
    float* ws  = (float*)d_ws;

    // workspace layout (floats): total ~32 MB + 4 KB
    float* Ebuf   = ws;                   // BMR*NPS      = 2,097,152
    float* Cbuf   = Ebuf  + 2097152;      // BMR*NPS      = 2,097,152
    float* xsbuf  = Cbuf  + 2097152;      // BB*NPS*DD    = 1,048,576
    float* hbuf   = xsbuf + 1048576;      // BB*NPS*FF    = 2,097,152
    float* ybuf   = hbuf  + 2097152;      // BB*NPS*DD    = 1,048,576
    float* colsum = ybuf  + 1048576;      // BB*NPS       = 1,024

    hipMemsetAsync(colsum, 0, BB * NPS * sizeof(float), stream);
    hipLaunchKernelGGL(k1_logits_kernel, dim3(512), dim3(256), 0, stream,
                       x, phi, Ebuf, Cbuf, colsum);
    hipLaunchKernelGGL(k2_xs_kernel, dim3(512), dim3(256), 0, stream,
                       Ebuf, x, colsum, xsbuf);
    hipLaunchKernelGGL(k3_ffn1_kernel, dim3(512), dim3(256), 0, stream,
                       xsbuf, w1, b1, hbuf);
    hipLaunchKernelGGL(k4_ffn2_kernel, dim3(512), dim3(256), 0, stream,
                       hbuf, w2, b2, ybuf);
    hipLaunchKernelGGL(k5_out_kernel, dim3(4096), dim3(256), 0, stream,
                       Cbuf, ybuf, out);
}